// Round 7
// baseline (118.926 us; speedup 1.0000x reference)
//
#include <hip/hip_runtime.h>
#include <hip/hip_bf16.h>

// R7 DIAGNOSTIC: identical R6 kernel launched 5x per call (same work every
// call; all launches write identical correct outputs). Purpose: dur_R7 =
// F + K_cold + 4*K_warm; combined with R6 (F + K_cold = 74.9us) this
// isolates K_warm, resolving whether the ~17us kernel cost is cold-cache
// fetch (K_warm small -> fix with W-stream warming) or structural gather
// serialization (K_warm ~= K_cold -> fix issue path).

#define NUM_FIELDS 26
#define ROWS_PER_GROUP 4
#define BLOCK 256
#define GROUPS_PER_BLOCK (BLOCK / 32)                       // 8
#define ROWS_PER_BLOCK (GROUPS_PER_BLOCK * ROWS_PER_GROUP)  // 32
#define INTS_PER_BLOCK (ROWS_PER_BLOCK * NUM_FIELDS)        // 832

__global__ __launch_bounds__(256) void FeaturesLinear_kernel(
    const int* __restrict__ x,        // (B, F) row-major
    const int* __restrict__ offsets,  // (F,)
    const float* __restrict__ W,      // (FEATURE_DIM, 1)
    const float* __restrict__ bias,   // (1,)
    float* __restrict__ out,          // (B, 1)
    int batch) {
  __shared__ int xs[INTS_PER_BLOCK];

  const int tid = threadIdx.x;
  const int block_row0 = blockIdx.x * ROWS_PER_BLOCK;
  const int* xb = x + block_row0 * NUM_FIELDS;

  // Coalesced stage of 32 rows (832 ints) into LDS.
#pragma unroll
  for (int i = 0; i < (INTS_PER_BLOCK + BLOCK - 1) / BLOCK; ++i) {
    int o = tid + i * BLOCK;
    if (o < INTS_PER_BLOCK) xs[o] = xb[o];
  }
  __syncthreads();

  const int l = tid & 31;   // lane in group = field
  const int g = tid >> 5;   // group -> 4 rows
  const int lc = (l < NUM_FIELDS) ? l : (NUM_FIELDS - 1);
  const int off = offsets[lc];

  // 4 independent gathers (ILP) per thread.
  int idx[ROWS_PER_GROUP];
#pragma unroll
  for (int r = 0; r < ROWS_PER_GROUP; ++r) {
    idx[r] = xs[(g * ROWS_PER_GROUP + r) * NUM_FIELDS + lc] + off;
  }
  float v[ROWS_PER_GROUP];
#pragma unroll
  for (int r = 0; r < ROWS_PER_GROUP; ++r) {
    float t = W[idx[r]];
    v[r] = (l < NUM_FIELDS) ? t : 0.f;
  }

  // Reduce each row-sum across the 32-lane group (4 independent trees).
#pragma unroll
  for (int m = 16; m > 0; m >>= 1) {
#pragma unroll
    for (int r = 0; r < ROWS_PER_GROUP; ++r) v[r] += __shfl_xor(v[r], m, 32);
  }

  // Lanes 0..3 write rows r=lane (static-index selection, rule #20).
  if (l < ROWS_PER_GROUP) {
    float wv = (l == 0) ? v[0] : (l == 1) ? v[1] : (l == 2) ? v[2] : v[3];
    out[block_row0 + g * ROWS_PER_GROUP + l] = wv + bias[0];
  }
}

extern "C" void kernel_launch(void* const* d_in, const int* in_sizes, int n_in,
                              void* d_out, int out_size, void* d_ws, size_t ws_size,
                              hipStream_t stream) {
  const int* x = (const int*)d_in[0];
  const int* offsets = (const int*)d_in[1];
  const float* W = (const float*)d_in[2];
  const float* bias = (const float*)d_in[3];
  float* out = (float*)d_out;

  int batch = in_sizes[0] / NUM_FIELDS;  // 65536

  dim3 grid(batch / ROWS_PER_BLOCK);  // 2048
  // 5 identical launches: launch 1 runs cold (post-restore/poison), launches
  // 2-5 run warm. (dur_R7 - dur_R6)/4 = K_warm.
  for (int rep = 0; rep < 5; ++rep) {
    FeaturesLinear_kernel<<<grid, dim3(BLOCK), 0, stream>>>(x, offsets, W, bias, out, batch);
  }
}

// Round 9
// 76.626 us; speedup vs baseline: 1.5520x; 1.5520x over previous
//
#include <hip/hip_runtime.h>
#include <hip/hip_bf16.h>

// FeaturesLinear: out[b] = sum_f W[x[b,f] + offsets[f]] + bias
// R8 (resubmit -- R8 hit GPUAcquisitionTimeout, never ran):
// R6 gather kernel + a warm-up prologue kernel that streams W linearly
// into L3 before the gather launches (stream-ordered). Every timed replay
// runs cold (harness re-poisons 268MB through L2/L3 first), so without this
// the gather pays ~65K random HBM line-fill latencies (~6us). A 0.7us
// sequential stream moves the table into the die-level Infinity Cache first.

#define NUM_FIELDS 26
#define ROWS_PER_GROUP 4
#define BLOCK 256
#define GROUPS_PER_BLOCK (BLOCK / 32)                       // 8
#define ROWS_PER_BLOCK (GROUPS_PER_BLOCK * ROWS_PER_GROUP)  // 32
#define INTS_PER_BLOCK (ROWS_PER_BLOCK * NUM_FIELDS)        // 832

// Prologue: linear stream of W to pre-fill L3. Values kept live via asm
// sink (rule #17: prevents DCE without cost).
__global__ __launch_bounds__(256) void warm_W_kernel(const float4* __restrict__ W4, int n4) {
  int i = blockIdx.x * blockDim.x + threadIdx.x;
  const int stride = gridDim.x * blockDim.x;
  for (; i < n4; i += stride) {
    float4 v = W4[i];
    asm volatile("" ::"v"(v.x), "v"(v.y), "v"(v.z), "v"(v.w));
  }
}

__global__ __launch_bounds__(256) void FeaturesLinear_kernel(
    const int* __restrict__ x,        // (B, F) row-major
    const int* __restrict__ offsets,  // (F,)
    const float* __restrict__ W,      // (FEATURE_DIM, 1)
    const float* __restrict__ bias,   // (1,)
    float* __restrict__ out,          // (B, 1)
    int batch) {
  __shared__ int xs[INTS_PER_BLOCK];

  const int tid = threadIdx.x;
  const int block_row0 = blockIdx.x * ROWS_PER_BLOCK;
  const int* xb = x + block_row0 * NUM_FIELDS;

  // Coalesced stage of 32 rows (832 ints) into LDS.
#pragma unroll
  for (int i = 0; i < (INTS_PER_BLOCK + BLOCK - 1) / BLOCK; ++i) {
    int o = tid + i * BLOCK;
    if (o < INTS_PER_BLOCK) xs[o] = xb[o];
  }
  __syncthreads();

  const int l = tid & 31;   // lane in group = field
  const int g = tid >> 5;   // group -> 4 rows
  const int lc = (l < NUM_FIELDS) ? l : (NUM_FIELDS - 1);
  const int off = offsets[lc];

  // 4 independent gathers (ILP) per thread.
  int idx[ROWS_PER_GROUP];
#pragma unroll
  for (int r = 0; r < ROWS_PER_GROUP; ++r) {
    idx[r] = xs[(g * ROWS_PER_GROUP + r) * NUM_FIELDS + lc] + off;
  }
  float v[ROWS_PER_GROUP];
#pragma unroll
  for (int r = 0; r < ROWS_PER_GROUP; ++r) {
    float t = W[idx[r]];
    v[r] = (l < NUM_FIELDS) ? t : 0.f;
  }

  // Reduce each row-sum across the 32-lane group (4 independent trees).
#pragma unroll
  for (int m = 16; m > 0; m >>= 1) {
#pragma unroll
    for (int r = 0; r < ROWS_PER_GROUP; ++r) v[r] += __shfl_xor(v[r], m, 32);
  }

  // Lanes 0..3 write rows r=lane (static-index selection, rule #20).
  if (l < ROWS_PER_GROUP) {
    float wv = (l == 0) ? v[0] : (l == 1) ? v[1] : (l == 2) ? v[2] : v[3];
    out[block_row0 + g * ROWS_PER_GROUP + l] = wv + bias[0];
  }
}

extern "C" void kernel_launch(void* const* d_in, const int* in_sizes, int n_in,
                              void* d_out, int out_size, void* d_ws, size_t ws_size,
                              hipStream_t stream) {
  const int* x = (const int*)d_in[0];
  const int* offsets = (const int*)d_in[1];
  const float* W = (const float*)d_in[2];
  const float* bias = (const float*)d_in[3];
  float* out = (float*)d_out;

  int batch = in_sizes[0] / NUM_FIELDS;  // 65536
  int n4 = in_sizes[2] / 4;              // 260000 float4

  // 1) Warm W into L3 (sequential stream, ~0.7us).
  warm_W_kernel<<<dim3(512), dim3(256), 0, stream>>>((const float4*)W, n4);

  // 2) Gather-reduce.
  dim3 grid(batch / ROWS_PER_BLOCK);  // 2048
  FeaturesLinear_kernel<<<grid, dim3(BLOCK), 0, stream>>>(x, offsets, W, bias, out, batch);
}